// Round 5
// baseline (3267.669 us; speedup 1.0000x reference)
//
#include <hip/hip_runtime.h>

// Problem constants
#define N_NODES 100000
#define N_EDGES 3200000
#define IN_CH   256
#define OUT_CH  128

// Bucketed-scatter parameters
#define NGROUP 8                     // staging partitions (~XCD count)
#define BNODE  128                   // nodes per bucket
#define NB     782                   // ceil(N_NODES/BNODE)
#define NSB    (NGROUP * NB)         // 6256 staging buckets
#define EPB    1024                  // edges per block (256 thr * 4)
#define NBLK_EDGE (N_EDGES / EPB)    // 3125

// ---------------------------------------------------------------------------
// Workspace layout (bytes):
//   xwb  [N_NODES*OUT_CH] bf16 : 25,600,000
//   wbf  [128][256]       bf16 :     65,536   (W^T, n-major)
//   bcnt [NSB]            i32  :     25,024
//   brp  [NSB+1]          i32  :     25,032
//   bcur [NSB]            i32  :     25,024
//   stg  [N_EDGES]        int2 : 25,600,000   {dst | slocal<<17, fp32 val}
// total = 51,340,616  (ws >= 78,000,016 proven in R2)
// ---------------------------------------------------------------------------
#define OFF_XWB  0
#define OFF_WBF  25600000
#define OFF_BCNT 25665536
#define OFF_BRP  25690560
#define OFF_BCUR 25715592
#define OFF_STG  25740616

typedef __attribute__((ext_vector_type(8))) short    bf8;
typedef __attribute__((ext_vector_type(4))) float    f4;
typedef __attribute__((ext_vector_type(4))) unsigned uv4;

__device__ __forceinline__ unsigned f2bf(float f) {   // fp32 -> bf16 (RNE)
    unsigned u = __float_as_uint(f);
    return (u + 0x7fffu + ((u >> 16) & 1u)) >> 16;
}

// ---------------------------------------------------------------------------
// W^T conversion: w[256][128] fp32 -> wbf[128][256] bf16 (n-major).
// ---------------------------------------------------------------------------
__global__ __launch_bounds__(256) void wcvt_kernel(const float* __restrict__ w,
                                                   unsigned short* __restrict__ wbf) {
    int t = threadIdx.x;
    int k = blockIdx.x * 2 + (t >> 7);
    int n = t & 127;
    wbf[n * 256 + k] = (unsigned short)f2bf(w[k * 128 + n]);
}

// ---------------------------------------------------------------------------
// MFMA GEMM: xw = x @ W (bf16 in, fp32 acc, bf16 out). Unchanged from R4.
// ---------------------------------------------------------------------------
__global__ __launch_bounds__(256) void gemm_kernel(const float* __restrict__ x,
                                                   const unsigned short* __restrict__ wbf,
                                                   unsigned* __restrict__ xwb) {
    int wave = threadIdx.x >> 6;
    int lane = threadIdx.x & 63;
    int m = lane & 15;
    int q = lane >> 4;
    int r0 = blockIdx.x * 64 + wave * 16;

    int arow = r0 + m;
    if (arow >= N_NODES) arow = N_NODES - 1;
    const float* xr = x + (long long)arow * IN_CH + q * 8;

    f4 acc[8];
#pragma unroll
    for (int ct = 0; ct < 8; ++ct) acc[ct] = (f4){0.f, 0.f, 0.f, 0.f};

#pragma unroll
    for (int ks = 0; ks < 8; ++ks) {
        float4 xa = *(const float4*)(xr + ks * 32);
        float4 xb = *(const float4*)(xr + ks * 32 + 4);
        bf8 a;
        a[0] = (short)f2bf(xa.x); a[1] = (short)f2bf(xa.y);
        a[2] = (short)f2bf(xa.z); a[3] = (short)f2bf(xa.w);
        a[4] = (short)f2bf(xb.x); a[5] = (short)f2bf(xb.y);
        a[6] = (short)f2bf(xb.z); a[7] = (short)f2bf(xb.w);
#pragma unroll
        for (int ct = 0; ct < 8; ++ct) {
            uv4 u = *(const uv4*)&wbf[(ct * 16 + m) * 256 + ks * 32 + q * 8];
            bf8 b = __builtin_bit_cast(bf8, u);
            acc[ct] = __builtin_amdgcn_mfma_f32_16x16x32_bf16(a, b, acc[ct], 0, 0, 0);
        }
    }

#pragma unroll
    for (int ct = 0; ct < 8; ++ct) {
#pragma unroll
        for (int r = 0; r < 4; ++r) {
            float v = acc[ct][r];
            float p = __shfl_xor(v, 1, 64);
            unsigned mine = f2bf(v), oth = f2bf(p);
            if (!(m & 1)) {
                int row = r0 + q * 4 + r;
                if (row < N_NODES)
                    xwb[row * 64 + ct * 8 + (m >> 1)] = mine | (oth << 16);
            }
        }
    }
}

// ---------------------------------------------------------------------------
// Bucket CSR: zero -> hist (6256 counters) -> scan -> bin scatter
// ---------------------------------------------------------------------------
__global__ __launch_bounds__(256) void bzero_kernel(int* __restrict__ bcnt) {
    int i = blockIdx.x * 256 + threadIdx.x;
    if (i < NSB) bcnt[i] = 0;
}

__global__ __launch_bounds__(256) void bhist_kernel(const int* __restrict__ src,
                                                    int* __restrict__ bcnt) {
    int g  = blockIdx.x & (NGROUP - 1);
    int e0 = blockIdx.x * EPB + threadIdx.x * 4;
    int4 s = *(const int4*)&src[e0];
    int* c = bcnt + g * NB;
    atomicAdd(&c[s.x >> 7], 1);
    atomicAdd(&c[s.y >> 7], 1);
    atomicAdd(&c[s.z >> 7], 1);
    atomicAdd(&c[s.w >> 7], 1);
}

// Single-block exclusive scan of 6256 counts (1024 thr x 8 elems = 8192 slots)
__global__ __launch_bounds__(1024) void bscan_kernel(const int* __restrict__ bcnt,
                                                     int* __restrict__ brp,
                                                     int* __restrict__ bcur) {
    __shared__ int wsum[16];
    int tid = threadIdx.x, lane = tid & 63, wid = tid >> 6;
    int i0 = tid * 8;
    int v[8]; int s8 = 0;
#pragma unroll
    for (int j = 0; j < 8; ++j) {
        int idx = i0 + j;
        v[j] = (idx < NSB) ? bcnt[idx] : 0;
        s8 += v[j];
    }
    int s = s8;
#pragma unroll
    for (int off = 1; off < 64; off <<= 1) {
        int t = __shfl_up(s, off, 64);
        if (lane >= off) s += t;
    }
    if (lane == 63) wsum[wid] = s;
    __syncthreads();
    if (wid == 0 && lane < 16) {
        int wv = wsum[lane];
#pragma unroll
        for (int off = 1; off < 16; off <<= 1) {
            int t = __shfl_up(wv, off, 64);
            if (lane >= off) wv += t;
        }
        wsum[lane] = wv;
    }
    __syncthreads();
    int excl = (wid ? wsum[wid - 1] : 0) + (s - s8);
#pragma unroll
    for (int j = 0; j < 8; ++j) {
        int idx = i0 + j;
        if (idx < NSB) { brp[idx] = excl; bcur[idx] = excl; }
        excl += v[j];
    }
    if (tid == 1023) brp[NSB] = wsum[15];
}

// Scatter edges into coarse buckets. Frontier = 782 lines/XCD -> L2-resident.
__global__ __launch_bounds__(256) void bin_kernel(const int* __restrict__ src,
                                                  const int* __restrict__ dst,
                                                  const float* __restrict__ val,
                                                  int* __restrict__ bcur,
                                                  int2* __restrict__ stg) {
    int g  = blockIdx.x & (NGROUP - 1);
    int e0 = blockIdx.x * EPB + threadIdx.x * 4;
    int4   s = *(const int4*)&src[e0];
    int4   d = *(const int4*)&dst[e0];
    float4 v = *(const float4*)&val[e0];
    int* cur = bcur + g * NB;
    int p;
    p = atomicAdd(&cur[s.x >> 7], 1);
    stg[p] = make_int2(d.x | ((s.x & 127) << 17), __float_as_int(v.x));
    p = atomicAdd(&cur[s.y >> 7], 1);
    stg[p] = make_int2(d.y | ((s.y & 127) << 17), __float_as_int(v.y));
    p = atomicAdd(&cur[s.z >> 7], 1);
    stg[p] = make_int2(d.z | ((s.z & 127) << 17), __float_as_int(v.z));
    p = atomicAdd(&cur[s.w >> 7], 1);
    stg[p] = make_int2(d.w | ((s.w & 127) << 17), __float_as_int(v.w));
}

// ---------------------------------------------------------------------------
// Bucket aggregate: one block per 128-node bucket. 64 KB LDS fp32 accumulator
// in even/odd-slot layout (lane -> bank lane&31: 2-way aliasing = free).
// Per edge: all-lane gather of xwb row (256 B), 2 ds_add_f32 per lane.
// Epilogue: un-interleave, add bias, coalesced float2 stores. No global atomics.
// ---------------------------------------------------------------------------
__global__ __launch_bounds__(256) void baggr_kernel(const int* __restrict__ brp,
                                                    const int2* __restrict__ stg,
                                                    const unsigned* __restrict__ xwb,
                                                    const float* __restrict__ bias,
                                                    float* __restrict__ out) {
    __shared__ float acc[BNODE * OUT_CH];   // 65536 B: [node][even ch 0..63 | odd ch 0..63]
    int tid = threadIdx.x, lane = tid & 63, wave = tid >> 6;
    int b = blockIdx.x;

#pragma unroll
    for (int i = 0; i < 16; ++i)
        ((float4*)acc)[i * 256 + tid] = make_float4(0.f, 0.f, 0.f, 0.f);
    __syncthreads();

#pragma unroll
    for (int gg = 0; gg < 2; ++gg) {
        int gi  = (wave * 2 + gg) * NB + b;
        int e   = brp[gi];
        int end = brp[gi + 1];
        for (; e + 4 <= end; e += 4) {
            int2 r0 = stg[e + 0];
            int2 r1 = stg[e + 1];
            int2 r2 = stg[e + 2];
            int2 r3 = stg[e + 3];
            unsigned u0 = xwb[(r0.x & 0x1FFFF) * 64 + lane];
            unsigned u1 = xwb[(r1.x & 0x1FFFF) * 64 + lane];
            unsigned u2 = xwb[(r2.x & 0x1FFFF) * 64 + lane];
            unsigned u3 = xwb[(r3.x & 0x1FFFF) * 64 + lane];
            int sl0 = (r0.x >> 17) & 127, sl1 = (r1.x >> 17) & 127;
            int sl2 = (r2.x >> 17) & 127, sl3 = (r3.x >> 17) & 127;
            float v0 = __int_as_float(r0.y), v1 = __int_as_float(r1.y);
            float v2 = __int_as_float(r2.y), v3 = __int_as_float(r3.y);
            atomicAdd(&acc[sl0 * 128 + lane],      v0 * __uint_as_float(u0 << 16));
            atomicAdd(&acc[sl0 * 128 + 64 + lane], v0 * __uint_as_float(u0 & 0xffff0000u));
            atomicAdd(&acc[sl1 * 128 + lane],      v1 * __uint_as_float(u1 << 16));
            atomicAdd(&acc[sl1 * 128 + 64 + lane], v1 * __uint_as_float(u1 & 0xffff0000u));
            atomicAdd(&acc[sl2 * 128 + lane],      v2 * __uint_as_float(u2 << 16));
            atomicAdd(&acc[sl2 * 128 + 64 + lane], v2 * __uint_as_float(u2 & 0xffff0000u));
            atomicAdd(&acc[sl3 * 128 + lane],      v3 * __uint_as_float(u3 << 16));
            atomicAdd(&acc[sl3 * 128 + 64 + lane], v3 * __uint_as_float(u3 & 0xffff0000u));
        }
        for (; e < end; ++e) {
            int2 r = stg[e];
            unsigned u = xwb[(r.x & 0x1FFFF) * 64 + lane];
            int sl = (r.x >> 17) & 127;
            float v = __int_as_float(r.y);
            atomicAdd(&acc[sl * 128 + lane],      v * __uint_as_float(u << 16));
            atomicAdd(&acc[sl * 128 + 64 + lane], v * __uint_as_float(u & 0xffff0000u));
        }
    }
    __syncthreads();

    int node0 = b * BNODE;
#pragma unroll
    for (int i = tid; i < BNODE * 64; i += 256) {
        int n = i >> 6, c = i & 63;
        int node = node0 + n;
        if (node < N_NODES) {
            float2 bv = *(const float2*)&bias[c * 2];
            float2 o;
            o.x = acc[n * 128 + c]      + bv.x;
            o.y = acc[n * 128 + 64 + c] + bv.y;
            *(float2*)&out[(long long)node * OUT_CH + c * 2] = o;
        }
    }
}

extern "C" void kernel_launch(void* const* d_in, const int* in_sizes, int n_in,
                              void* d_out, int out_size, void* d_ws, size_t ws_size,
                              hipStream_t stream) {
    const float* x     = (const float*)d_in[0];
    const int*   esrc  = (const int*)d_in[1];
    const int*   edst  = (const int*)d_in[2];
    const float* evals = (const float*)d_in[3];
    const float* w     = (const float*)d_in[4];
    const float* bias  = (const float*)d_in[5];
    float* out = (float*)d_out;

    char* ws = (char*)d_ws;
    unsigned*       xwb  = (unsigned*)      (ws + OFF_XWB);
    unsigned short* wbf  = (unsigned short*)(ws + OFF_WBF);
    int*            bcnt = (int*)           (ws + OFF_BCNT);
    int*            brp  = (int*)           (ws + OFF_BRP);
    int*            bcur = (int*)           (ws + OFF_BCUR);
    int2*           stg  = (int2*)          (ws + OFF_STG);

    wcvt_kernel<<<128, 256, 0, stream>>>(w, wbf);
    gemm_kernel<<<(N_NODES + 63) / 64, 256, 0, stream>>>(x, wbf, xwb);
    bzero_kernel<<<(NSB + 255) / 256, 256, 0, stream>>>(bcnt);
    bhist_kernel<<<NBLK_EDGE, 256, 0, stream>>>(esrc, bcnt);
    bscan_kernel<<<1, 1024, 0, stream>>>(bcnt, brp, bcur);
    bin_kernel<<<NBLK_EDGE, 256, 0, stream>>>(esrc, edst, evals, bcur, stg);
    baggr_kernel<<<NB, 256, 0, stream>>>(brp, stg, xwb, bias, out);
}

// Round 6
// 823.714 us; speedup vs baseline: 3.9670x; 3.9670x over previous
//
#include <hip/hip_runtime.h>

// Problem constants
#define N_NODES 100000
#define N_EDGES 3200000
#define IN_CH   256
#define OUT_CH  128

// Bucketed-sort parameters
#define NGROUP 8                     // staging partitions (~XCD count)
#define BNODE  128                   // nodes per bucket
#define NB     782                   // ceil(N_NODES/BNODE)
#define NSB    (NB * NGROUP)         // 6256 buckets, BUCKET-MAJOR: idx = b*8+g
#define SBUF   6144                  // LDS sort capacity (avg bucket = 4092)
#define EPB    1024                  // edges per block (256 thr * 4)
#define NBLK_EDGE (N_EDGES / EPB)    // 3125

// ---------------------------------------------------------------------------
// Workspace layout (bytes):
//   xwb  [N_NODES*OUT_CH] bf16 : 25,600,000
//   wbf  [128][256]       bf16 :     65,536
//   bcnt [NSB]            i32  :     25,024
//   brp  [NSB+1]          i32  :     25,032
//   bcur [NSB]            i32  :     25,024
//   rp   [N_NODES+1]      i32  :    400,016
//   stg  [N_EDGES]        int2 : 25,600,000  (binned, then node-sorted in place)
// total = 51,740,632  (ws >= 78,000,016 proven in R2)
// ---------------------------------------------------------------------------
#define OFF_XWB  0
#define OFF_WBF  25600000
#define OFF_BCNT 25665536
#define OFF_BRP  25690560
#define OFF_BCUR 25715592
#define OFF_RP   25740616
#define OFF_STG  26140632

typedef __attribute__((ext_vector_type(8))) short    bf8;
typedef __attribute__((ext_vector_type(4))) float    f4;
typedef __attribute__((ext_vector_type(4))) unsigned uv4;

__device__ __forceinline__ unsigned f2bf(float f) {   // fp32 -> bf16 (RNE)
    unsigned u = __float_as_uint(f);
    return (u + 0x7fffu + ((u >> 16) & 1u)) >> 16;
}

// ---------------------------------------------------------------------------
// W^T conversion: w[256][128] fp32 -> wbf[128][256] bf16 (n-major).
// ---------------------------------------------------------------------------
__global__ __launch_bounds__(256) void wcvt_kernel(const float* __restrict__ w,
                                                   unsigned short* __restrict__ wbf) {
    int t = threadIdx.x;
    int k = blockIdx.x * 2 + (t >> 7);
    int n = t & 127;
    wbf[n * 256 + k] = (unsigned short)f2bf(w[k * 128 + n]);
}

// ---------------------------------------------------------------------------
// MFMA GEMM: xw = x @ W (bf16 in, fp32 acc, bf16 out). Unchanged from R4.
// ---------------------------------------------------------------------------
__global__ __launch_bounds__(256) void gemm_kernel(const float* __restrict__ x,
                                                   const unsigned short* __restrict__ wbf,
                                                   unsigned* __restrict__ xwb) {
    int wave = threadIdx.x >> 6;
    int lane = threadIdx.x & 63;
    int m = lane & 15;
    int q = lane >> 4;
    int r0 = blockIdx.x * 64 + wave * 16;

    int arow = r0 + m;
    if (arow >= N_NODES) arow = N_NODES - 1;
    const float* xr = x + (long long)arow * IN_CH + q * 8;

    f4 acc[8];
#pragma unroll
    for (int ct = 0; ct < 8; ++ct) acc[ct] = (f4){0.f, 0.f, 0.f, 0.f};

#pragma unroll
    for (int ks = 0; ks < 8; ++ks) {
        float4 xa = *(const float4*)(xr + ks * 32);
        float4 xb = *(const float4*)(xr + ks * 32 + 4);
        bf8 a;
        a[0] = (short)f2bf(xa.x); a[1] = (short)f2bf(xa.y);
        a[2] = (short)f2bf(xa.z); a[3] = (short)f2bf(xa.w);
        a[4] = (short)f2bf(xb.x); a[5] = (short)f2bf(xb.y);
        a[6] = (short)f2bf(xb.z); a[7] = (short)f2bf(xb.w);
#pragma unroll
        for (int ct = 0; ct < 8; ++ct) {
            uv4 u = *(const uv4*)&wbf[(ct * 16 + m) * 256 + ks * 32 + q * 8];
            bf8 b = __builtin_bit_cast(bf8, u);
            acc[ct] = __builtin_amdgcn_mfma_f32_16x16x32_bf16(a, b, acc[ct], 0, 0, 0);
        }
    }

#pragma unroll
    for (int ct = 0; ct < 8; ++ct) {
#pragma unroll
        for (int r = 0; r < 4; ++r) {
            float v = acc[ct][r];
            float p = __shfl_xor(v, 1, 64);
            unsigned mine = f2bf(v), oth = f2bf(p);
            if (!(m & 1)) {
                int row = r0 + q * 4 + r;
                if (row < N_NODES)
                    xwb[row * 64 + ct * 8 + (m >> 1)] = mine | (oth << 16);
            }
        }
    }
}

// ---------------------------------------------------------------------------
// Bucket binning: zero -> hist(6256) -> scan -> bin scatter (bucket-major)
// ---------------------------------------------------------------------------
__global__ __launch_bounds__(256) void bzero_kernel(int* __restrict__ bcnt) {
    int i = blockIdx.x * 256 + threadIdx.x;
    if (i < NSB) bcnt[i] = 0;
}

__global__ __launch_bounds__(256) void bhist_kernel(const int* __restrict__ src,
                                                    int* __restrict__ bcnt) {
    int g  = blockIdx.x & (NGROUP - 1);
    int e0 = blockIdx.x * EPB + threadIdx.x * 4;
    int4 s = *(const int4*)&src[e0];
    atomicAdd(&bcnt[(s.x >> 7) * NGROUP + g], 1);
    atomicAdd(&bcnt[(s.y >> 7) * NGROUP + g], 1);
    atomicAdd(&bcnt[(s.z >> 7) * NGROUP + g], 1);
    atomicAdd(&bcnt[(s.w >> 7) * NGROUP + g], 1);
}

// Single-block exclusive scan of NSB counts (1024 thr x 8 = 8192 slots)
__global__ __launch_bounds__(1024) void bscan_kernel(const int* __restrict__ bcnt,
                                                     int* __restrict__ brp,
                                                     int* __restrict__ bcur) {
    __shared__ int wsum[16];
    int tid = threadIdx.x, lane = tid & 63, wid = tid >> 6;
    int i0 = tid * 8;
    int v[8]; int s8 = 0;
#pragma unroll
    for (int j = 0; j < 8; ++j) {
        int idx = i0 + j;
        v[j] = (idx < NSB) ? bcnt[idx] : 0;
        s8 += v[j];
    }
    int s = s8;
#pragma unroll
    for (int off = 1; off < 64; off <<= 1) {
        int t = __shfl_up(s, off, 64);
        if (lane >= off) s += t;
    }
    if (lane == 63) wsum[wid] = s;
    __syncthreads();
    if (wid == 0 && lane < 16) {
        int wv = wsum[lane];
#pragma unroll
        for (int off = 1; off < 16; off <<= 1) {
            int t = __shfl_up(wv, off, 64);
            if (lane >= off) wv += t;
        }
        wsum[lane] = wv;
    }
    __syncthreads();
    int excl = (wid ? wsum[wid - 1] : 0) + (s - s8);
#pragma unroll
    for (int j = 0; j < 8; ++j) {
        int idx = i0 + j;
        if (idx < NSB) { brp[idx] = excl; bcur[idx] = excl; }
        excl += v[j];
    }
    if (tid == 1023) brp[NSB] = wsum[15];
}

// Scatter edges into coarse buckets (bucket-major). Frontier ~400 KB, and
// region (b,g) is written only from blocks with blockIdx&7==g (XCD-local).
__global__ __launch_bounds__(256) void bin_kernel(const int* __restrict__ src,
                                                  const int* __restrict__ dst,
                                                  const float* __restrict__ val,
                                                  int* __restrict__ bcur,
                                                  int2* __restrict__ stg) {
    int g  = blockIdx.x & (NGROUP - 1);
    int e0 = blockIdx.x * EPB + threadIdx.x * 4;
    int4   s = *(const int4*)&src[e0];
    int4   d = *(const int4*)&dst[e0];
    float4 v = *(const float4*)&val[e0];
    int p;
    p = atomicAdd(&bcur[(s.x >> 7) * NGROUP + g], 1);
    stg[p] = make_int2(d.x | ((s.x & 127) << 17), __float_as_int(v.x));
    p = atomicAdd(&bcur[(s.y >> 7) * NGROUP + g], 1);
    stg[p] = make_int2(d.y | ((s.y & 127) << 17), __float_as_int(v.y));
    p = atomicAdd(&bcur[(s.z >> 7) * NGROUP + g], 1);
    stg[p] = make_int2(d.z | ((s.z & 127) << 17), __float_as_int(v.z));
    p = atomicAdd(&bcur[(s.w >> 7) * NGROUP + g], 1);
    stg[p] = make_int2(d.w | ((s.w & 127) << 17), __float_as_int(v.w));
}

// ---------------------------------------------------------------------------
// Per-bucket node sort (in place): one block per bucket. Local 128-counter
// hist in LDS -> wave scan -> LDS scatter -> coalesced write-back (sorted by
// node, slocal stripped) + node-exact rp. Write amplification ~1x.
// ---------------------------------------------------------------------------
__global__ __launch_bounds__(256) void sortb_kernel(const int* __restrict__ brp,
                                                    int2* __restrict__ stg,
                                                    int* __restrict__ rp) {
    __shared__ int  cnt[BNODE];     // hist -> exclusive offsets
    __shared__ int  cur[BNODE];
    __shared__ int2 sbuf[SBUF];
    int b = blockIdx.x, tid = threadIdx.x;
    int e0  = brp[b * NGROUP];
    int e1  = (b == NB - 1) ? N_EDGES : brp[(b + 1) * NGROUP];
    int len = e1 - e0;

    if (tid < BNODE) cnt[tid] = 0;
    __syncthreads();

    for (int i = tid; i < len; i += 256)
        atomicAdd(&cnt[(stg[e0 + i].x >> 17) & 127], 1);
    __syncthreads();

    if (tid < 64) {                 // wave 0: exclusive scan of 128 counters
        int v0 = cnt[tid], v1 = cnt[64 + tid];
        int s0 = v0;
#pragma unroll
        for (int off = 1; off < 64; off <<= 1) {
            int t = __shfl_up(s0, off, 64);
            if (tid >= off) s0 += t;
        }
        int tot0 = __shfl(s0, 63, 64);
        int s1 = v1;
#pragma unroll
        for (int off = 1; off < 64; off <<= 1) {
            int t = __shfl_up(s1, off, 64);
            if (tid >= off) s1 += t;
        }
        cnt[tid]      = s0 - v0;            // exclusive
        cnt[64 + tid] = tot0 + s1 - v1;
        cur[tid]      = s0 - v0;
        cur[64 + tid] = tot0 + s1 - v1;
    }
    __syncthreads();

    for (int i = tid; i < len; i += 256) {
        int2 r = stg[e0 + i];
        int key = (r.x >> 17) & 127;
        int p = atomicAdd(&cur[key], 1);
        if (p < SBUF) sbuf[p] = make_int2(r.x & 0x1FFFF, r.y);
    }
    __syncthreads();

    for (int i = tid; i < len; i += 256) stg[e0 + i] = sbuf[i];

    if (tid < BNODE) {
        int node = b * BNODE + tid;
        if (node < N_NODES) rp[node] = e0 + cnt[tid];
    }
    if (b == 0 && tid == 0) rp[N_NODES] = N_EDGES;
}

// ---------------------------------------------------------------------------
// Aggregate: one node per wave, node-contiguous sorted edges, 8-wide unroll
// for gather MLP; bf16x2 gathers, fp32 accumulate, bias fused.
// ---------------------------------------------------------------------------
__global__ __launch_bounds__(256) void aggregate_kernel(const int* __restrict__ rp,
                                                        const int2* __restrict__ stg,
                                                        const unsigned* __restrict__ xwb,
                                                        const float* __restrict__ bias,
                                                        float* __restrict__ out) {
    int node = blockIdx.x * 4 + (threadIdx.x >> 6);
    int lane = threadIdx.x & 63;
    float2 acc = *(const float2*)&bias[lane * 2];

    int e   = rp[node];
    int end = rp[node + 1];
    for (; e + 8 <= end; e += 8) {
        int2 r0 = stg[e + 0]; int2 r1 = stg[e + 1];
        int2 r2 = stg[e + 2]; int2 r3 = stg[e + 3];
        int2 r4 = stg[e + 4]; int2 r5 = stg[e + 5];
        int2 r6 = stg[e + 6]; int2 r7 = stg[e + 7];
        unsigned u0 = xwb[r0.x * 64 + lane];
        unsigned u1 = xwb[r1.x * 64 + lane];
        unsigned u2 = xwb[r2.x * 64 + lane];
        unsigned u3 = xwb[r3.x * 64 + lane];
        unsigned u4 = xwb[r4.x * 64 + lane];
        unsigned u5 = xwb[r5.x * 64 + lane];
        unsigned u6 = xwb[r6.x * 64 + lane];
        unsigned u7 = xwb[r7.x * 64 + lane];
        float v0 = __int_as_float(r0.y), v1 = __int_as_float(r1.y);
        float v2 = __int_as_float(r2.y), v3 = __int_as_float(r3.y);
        float v4 = __int_as_float(r4.y), v5 = __int_as_float(r5.y);
        float v6 = __int_as_float(r6.y), v7 = __int_as_float(r7.y);
        acc.x += v0 * __uint_as_float(u0 << 16);
        acc.y += v0 * __uint_as_float(u0 & 0xffff0000u);
        acc.x += v1 * __uint_as_float(u1 << 16);
        acc.y += v1 * __uint_as_float(u1 & 0xffff0000u);
        acc.x += v2 * __uint_as_float(u2 << 16);
        acc.y += v2 * __uint_as_float(u2 & 0xffff0000u);
        acc.x += v3 * __uint_as_float(u3 << 16);
        acc.y += v3 * __uint_as_float(u3 & 0xffff0000u);
        acc.x += v4 * __uint_as_float(u4 << 16);
        acc.y += v4 * __uint_as_float(u4 & 0xffff0000u);
        acc.x += v5 * __uint_as_float(u5 << 16);
        acc.y += v5 * __uint_as_float(u5 & 0xffff0000u);
        acc.x += v6 * __uint_as_float(u6 << 16);
        acc.y += v6 * __uint_as_float(u6 & 0xffff0000u);
        acc.x += v7 * __uint_as_float(u7 << 16);
        acc.y += v7 * __uint_as_float(u7 & 0xffff0000u);
    }
    for (; e < end; ++e) {
        int2 r = stg[e];
        unsigned u = xwb[r.x * 64 + lane];
        float v = __int_as_float(r.y);
        acc.x += v * __uint_as_float(u << 16);
        acc.y += v * __uint_as_float(u & 0xffff0000u);
    }
    *(float2*)&out[(long long)node * OUT_CH + lane * 2] = acc;
}

extern "C" void kernel_launch(void* const* d_in, const int* in_sizes, int n_in,
                              void* d_out, int out_size, void* d_ws, size_t ws_size,
                              hipStream_t stream) {
    const float* x     = (const float*)d_in[0];
    const int*   esrc  = (const int*)d_in[1];
    const int*   edst  = (const int*)d_in[2];
    const float* evals = (const float*)d_in[3];
    const float* w     = (const float*)d_in[4];
    const float* bias  = (const float*)d_in[5];
    float* out = (float*)d_out;

    char* ws = (char*)d_ws;
    unsigned*       xwb  = (unsigned*)      (ws + OFF_XWB);
    unsigned short* wbf  = (unsigned short*)(ws + OFF_WBF);
    int*            bcnt = (int*)           (ws + OFF_BCNT);
    int*            brp  = (int*)           (ws + OFF_BRP);
    int*            bcur = (int*)           (ws + OFF_BCUR);
    int*            rp   = (int*)           (ws + OFF_RP);
    int2*           stg  = (int2*)          (ws + OFF_STG);

    wcvt_kernel<<<128, 256, 0, stream>>>(w, wbf);
    gemm_kernel<<<(N_NODES + 63) / 64, 256, 0, stream>>>(x, wbf, xwb);
    bzero_kernel<<<(NSB + 255) / 256, 256, 0, stream>>>(bcnt);
    bhist_kernel<<<NBLK_EDGE, 256, 0, stream>>>(esrc, bcnt);
    bscan_kernel<<<1, 1024, 0, stream>>>(bcnt, brp, bcur);
    bin_kernel<<<NBLK_EDGE, 256, 0, stream>>>(esrc, edst, evals, bcur, stg);
    sortb_kernel<<<NB, 256, 0, stream>>>(brp, stg, rp);
    aggregate_kernel<<<N_NODES / 4, 256, 0, stream>>>(rp, stg, xwb, bias, out);
}